// Round 3
// baseline (144.233 us; speedup 1.0000x reference)
//
#include <hip/hip_runtime.h>
#include <math.h>

#define N_GRAPHS 4096
#define LATENT 32

__device__ __forceinline__ float fast_tanh(float x) {
    // tanh(x) = (e^{2x}-1)/(e^{2x}+1); clamp so exp can't overflow
    x = fminf(fmaxf(x, -15.f), 15.f);
    float e = __expf(2.f * x);
    return (e - 1.f) / (e + 1.f);
}

// Zero the 33*N_GRAPHS-float accumulator workspace
__global__ __launch_bounds__(256) void zero_ws_kernel(float4* __restrict__ ws) {
    ws[blockIdx.x * 256 + threadIdx.x] = float4{0.f, 0.f, 0.f, 0.f};
}

// Fused: per-node attention score + exp + segmented (sorted-batch) weighted sums.
// se[g]  += sum_i e_i          (i in graph g)
// sez[g] += sum_i e_i * z_i    (32-vector)
__global__ __launch_bounds__(256) void attn_seg_kernel(
    const float* __restrict__ z, const int* __restrict__ batch,
    const float* __restrict__ w1, const float* __restrict__ b1,
    const float* __restrict__ w2, const float* __restrict__ b2,
    float* __restrict__ se, float* __restrict__ sez, int n)
{
    int i = blockIdx.x * blockDim.x + threadIdx.x;
    int lane = threadIdx.x & 63;
    int iL = (i < n) ? i : (n - 1);       // clamp: extra lanes contribute e=0
    int g = batch[iL];

    // load this node's 32 latent values (wave reads contiguous 8KB)
    float zr[32];
    const float4* zp = reinterpret_cast<const float4*>(z + (size_t)iL * LATENT);
    #pragma unroll
    for (int q = 0; q < 8; ++q) {
        float4 v = zp[q];
        zr[4*q+0] = v.x; zr[4*q+1] = v.y; zr[4*q+2] = v.z; zr[4*q+3] = v.w;
    }

    // alpha_raw = tanh(z @ W1 + b1) @ w2 + b2
    // k-outer, j in groups of 8: w1 row-chunk loads are 8 contiguous floats
    // -> LLVM merges to s_load_dwordx8 (scalar ops per wave: 1024 -> ~128)
    float alpha = b2[0];
    #pragma unroll
    for (int jg = 0; jg < 4; ++jg) {
        float acc[8];
        #pragma unroll
        for (int j = 0; j < 8; ++j) acc[j] = b1[jg*8 + j];
        #pragma unroll
        for (int k = 0; k < LATENT; ++k) {
            const float* wrow = w1 + k*LATENT + jg*8;   // contiguous 8
            #pragma unroll
            for (int j = 0; j < 8; ++j)
                acc[j] = fmaf(zr[k], wrow[j], acc[j]);
        }
        #pragma unroll
        for (int j = 0; j < 8; ++j)
            alpha = fmaf(fast_tanh(acc[j]), w2[jg*8 + j], alpha);
    }
    // global-max subtraction cancels in the per-graph normalization; skip it.
    float e = (i < n) ? __expf(alpha) : 0.f;

    // values to segment-sum: v[0]=e, v[1..32]=e*z[k]
    float v[33];
    v[0] = e;
    #pragma unroll
    for (int k = 0; k < LATENT; ++k) v[k+1] = e * zr[k];

    // wave-level segmented inclusive scan (batch is sorted -> contiguous runs)
    #pragma unroll
    for (int s = 1; s < 64; s <<= 1) {
        int gprev = __shfl_up(g, s);
        bool doadd = (lane >= s) && (gprev == g);
        #pragma unroll
        for (int t = 0; t < 33; ++t) {
            float vv = __shfl_up(v[t], s);
            if (doadd) v[t] += vv;
        }
    }
    // segment tails flush to global accumulators
    int gnext = __shfl_down(g, 1);
    bool tail = (lane == 63) || (gnext != g);
    if (tail) {
        atomicAdd(&se[g], v[0]);
        #pragma unroll
        for (int k = 0; k < LATENT; ++k)
            atomicAdd(&sez[g*LATENT + k], v[k+1]);
    }
}

// One wave per graph: graph_z = sez/(se+1e-8); 32->128->64->1 MLP with sigmoid.
__global__ __launch_bounds__(64) void mlp_kernel(
    const float* __restrict__ se, const float* __restrict__ sez,
    const float* __restrict__ m1w, const float* __restrict__ m1b,
    const float* __restrict__ m2w, const float* __restrict__ m2b,
    const float* __restrict__ m3w, const float* __restrict__ m3b,
    float* __restrict__ out)
{
    int gidx = blockIdx.x;
    int lane = threadIdx.x;
    float inv = 1.f / (se[gidx] + 1e-8f);
    float gz = (lane < LATENT) ? sez[gidx*LATENT + lane] * inv : 0.f;

    // layer 1: 32 -> 128 ; lane holds hidden[lane] (a0) and hidden[lane+64] (a1)
    float a0 = m1b[lane], a1 = m1b[lane + 64];
    #pragma unroll
    for (int k = 0; k < LATENT; ++k) {
        float zk = __shfl(gz, k);
        a0 = fmaf(zk, m1w[k*128 + lane], a0);
        a1 = fmaf(zk, m1w[k*128 + lane + 64], a1);
    }
    a0 = fmaxf(a0, 0.f); a1 = fmaxf(a1, 0.f);

    // layer 2: 128 -> 64 ; lane holds out2[lane]
    float b = m2b[lane];
    #pragma unroll
    for (int k = 0; k < 64; ++k) {
        float xk = __shfl(a0, k);
        b = fmaf(xk, m2w[k*64 + lane], b);
    }
    #pragma unroll
    for (int k = 0; k < 64; ++k) {
        float xk = __shfl(a1, k);
        b = fmaf(xk, m2w[(k+64)*64 + lane], b);
    }
    b = fmaxf(b, 0.f);

    // layer 3: 64 -> 1 ; butterfly reduce, sigmoid
    float p = b * m3w[lane];
    #pragma unroll
    for (int s = 32; s >= 1; s >>= 1)
        p += __shfl_xor(p, s);
    if (lane == 0)
        out[gidx] = 1.f / (1.f + __expf(-(p + m3b[0])));
}

extern "C" void kernel_launch(void* const* d_in, const int* in_sizes, int n_in,
                              void* d_out, int out_size, void* d_ws, size_t ws_size,
                              hipStream_t stream)
{
    const float* z    = (const float*)d_in[0];
    const int*   batch= (const int*)d_in[1];
    const float* aw1  = (const float*)d_in[2];
    const float* ab1  = (const float*)d_in[3];
    const float* aw2  = (const float*)d_in[4];
    const float* ab2  = (const float*)d_in[5];
    const float* m1w  = (const float*)d_in[6];
    const float* m1b  = (const float*)d_in[7];
    const float* m2w  = (const float*)d_in[8];
    const float* m2b  = (const float*)d_in[9];
    const float* m3w  = (const float*)d_in[10];
    const float* m3b  = (const float*)d_in[11];
    float* out = (float*)d_out;

    int n = in_sizes[0] / LATENT;   // 2,000,000 nodes

    float* se  = (float*)d_ws;          // [4096]
    float* sez = se + N_GRAPHS;         // [4096][32]

    // N_GRAPHS*33 floats = 135168 floats = 33792 float4 = 132 blocks * 256
    zero_ws_kernel<<<132, 256, 0, stream>>>((float4*)d_ws);

    int blocks = (n + 255) / 256;
    attn_seg_kernel<<<blocks, 256, 0, stream>>>(z, batch, aw1, ab1, aw2, ab2, se, sez, n);
    mlp_kernel<<<N_GRAPHS, 64, 0, stream>>>(se, sez, m1w, m1b, m2w, m2b, m3w, m3b, out);
}

// Round 4
// 144.015 us; speedup vs baseline: 1.0015x; 1.0015x over previous
//
#include <hip/hip_runtime.h>
#include <math.h>

#define N_GRAPHS 4096
#define LATENT 32

__device__ __forceinline__ float fast_tanh(float x) {
    // tanh(x) = (e^{2x}-1)/(e^{2x}+1); clamp so exp can't overflow
    x = fminf(fmaxf(x, -15.f), 15.f);
    float e = __expf(2.f * x);
    return (e - 1.f) / (e + 1.f);
}

// Zero the 33*N_GRAPHS-float accumulator workspace
__global__ __launch_bounds__(256) void zero_ws_kernel(float4* __restrict__ ws) {
    ws[blockIdx.x * 256 + threadIdx.x] = float4{0.f, 0.f, 0.f, 0.f};
}

// Fused: per-node attention score + exp + segmented (sorted-batch) weighted sums.
// se[g]  += sum_i e_i          (i in graph g)
// sez[g] += sum_i e_i * z_i    (32-vector)
// launch_bounds(256,2): allow ~256 VGPRs -> keep zr[32]/v[33] in registers
// (round-3 compiled to 36 VGPRs and spilled everything; VALU 2.4x inflated)
__global__ __launch_bounds__(256, 2) void attn_seg_kernel(
    const float* __restrict__ z, const int* __restrict__ batch,
    const float* __restrict__ w1, const float* __restrict__ b1,
    const float* __restrict__ w2, const float* __restrict__ b2,
    float* __restrict__ se, float* __restrict__ sez, int n)
{
    int i = blockIdx.x * blockDim.x + threadIdx.x;
    int lane = threadIdx.x & 63;
    int iL = (i < n) ? i : (n - 1);       // clamp: extra lanes contribute e=0
    int g = batch[iL];

    // load this node's 32 latent values (wave reads contiguous 8KB)
    float zr[32];
    const float4* zp = reinterpret_cast<const float4*>(z + (size_t)iL * LATENT);
    #pragma unroll
    for (int q = 0; q < 8; ++q) {
        float4 v = zp[q];
        zr[4*q+0] = v.x; zr[4*q+1] = v.y; zr[4*q+2] = v.z; zr[4*q+3] = v.w;
    }

    // alpha_raw = tanh(z @ W1 + b1) @ w2 + b2
    // k-outer, j in groups of 8: w1 row-chunk loads are 8 contiguous floats
    // -> merged scalar loads (s_load_dwordx8)
    float alpha = b2[0];
    #pragma unroll
    for (int jg = 0; jg < 4; ++jg) {
        float acc[8];
        #pragma unroll
        for (int j = 0; j < 8; ++j) acc[j] = b1[jg*8 + j];
        #pragma unroll
        for (int k = 0; k < LATENT; ++k) {
            const float* wrow = w1 + k*LATENT + jg*8;   // contiguous 8
            #pragma unroll
            for (int j = 0; j < 8; ++j)
                acc[j] = fmaf(zr[k], wrow[j], acc[j]);
        }
        #pragma unroll
        for (int j = 0; j < 8; ++j)
            alpha = fmaf(fast_tanh(acc[j]), w2[jg*8 + j], alpha);
    }
    // global-max subtraction cancels in the per-graph normalization; skip it.
    float e = (i < n) ? __expf(alpha) : 0.f;

    // values to segment-sum: v[0]=e, v[1..32]=e*z[k]
    float v[33];
    v[0] = e;
    #pragma unroll
    for (int k = 0; k < LATENT; ++k) v[k+1] = e * zr[k];

    // wave-level segmented inclusive scan (batch is sorted -> contiguous runs)
    // guard as a 0/1 multiplier: one cndmask per step, fma per element
    #pragma unroll
    for (int s = 1; s < 64; s <<= 1) {
        int gprev = __shfl_up(g, s);
        float m = ((lane >= s) && (gprev == g)) ? 1.f : 0.f;
        #pragma unroll
        for (int t = 0; t < 33; ++t) {
            float vv = __shfl_up(v[t], s);
            v[t] = fmaf(m, vv, v[t]);
        }
    }
    // segment tails flush to global accumulators
    int gnext = __shfl_down(g, 1);
    bool tail = (lane == 63) || (gnext != g);
    if (tail) {
        atomicAdd(&se[g], v[0]);
        #pragma unroll
        for (int k = 0; k < LATENT; ++k)
            atomicAdd(&sez[g*LATENT + k], v[k+1]);
    }
}

// One wave per graph: graph_z = sez/(se+1e-8); 32->128->64->1 MLP with sigmoid.
__global__ __launch_bounds__(64) void mlp_kernel(
    const float* __restrict__ se, const float* __restrict__ sez,
    const float* __restrict__ m1w, const float* __restrict__ m1b,
    const float* __restrict__ m2w, const float* __restrict__ m2b,
    const float* __restrict__ m3w, const float* __restrict__ m3b,
    float* __restrict__ out)
{
    int gidx = blockIdx.x;
    int lane = threadIdx.x;
    float inv = 1.f / (se[gidx] + 1e-8f);
    float gz = (lane < LATENT) ? sez[gidx*LATENT + lane] * inv : 0.f;

    // layer 1: 32 -> 128 ; lane holds hidden[lane] (a0) and hidden[lane+64] (a1)
    float a0 = m1b[lane], a1 = m1b[lane + 64];
    #pragma unroll
    for (int k = 0; k < LATENT; ++k) {
        float zk = __shfl(gz, k);
        a0 = fmaf(zk, m1w[k*128 + lane], a0);
        a1 = fmaf(zk, m1w[k*128 + lane + 64], a1);
    }
    a0 = fmaxf(a0, 0.f); a1 = fmaxf(a1, 0.f);

    // layer 2: 128 -> 64 ; lane holds out2[lane]
    float b = m2b[lane];
    #pragma unroll
    for (int k = 0; k < 64; ++k) {
        float xk = __shfl(a0, k);
        b = fmaf(xk, m2w[k*64 + lane], b);
    }
    #pragma unroll
    for (int k = 0; k < 64; ++k) {
        float xk = __shfl(a1, k);
        b = fmaf(xk, m2w[(k+64)*64 + lane], b);
    }
    b = fmaxf(b, 0.f);

    // layer 3: 64 -> 1 ; butterfly reduce, sigmoid
    float p = b * m3w[lane];
    #pragma unroll
    for (int s = 32; s >= 1; s >>= 1)
        p += __shfl_xor(p, s);
    if (lane == 0)
        out[gidx] = 1.f / (1.f + __expf(-(p + m3b[0])));
}

extern "C" void kernel_launch(void* const* d_in, const int* in_sizes, int n_in,
                              void* d_out, int out_size, void* d_ws, size_t ws_size,
                              hipStream_t stream)
{
    const float* z    = (const float*)d_in[0];
    const int*   batch= (const int*)d_in[1];
    const float* aw1  = (const float*)d_in[2];
    const float* ab1  = (const float*)d_in[3];
    const float* aw2  = (const float*)d_in[4];
    const float* ab2  = (const float*)d_in[5];
    const float* m1w  = (const float*)d_in[6];
    const float* m1b  = (const float*)d_in[7];
    const float* m2w  = (const float*)d_in[8];
    const float* m2b  = (const float*)d_in[9];
    const float* m3w  = (const float*)d_in[10];
    const float* m3b  = (const float*)d_in[11];
    float* out = (float*)d_out;

    int n = in_sizes[0] / LATENT;   // 2,000,000 nodes

    float* se  = (float*)d_ws;          // [4096]
    float* sez = se + N_GRAPHS;         // [4096][32]

    // N_GRAPHS*33 floats = 135168 floats = 33792 float4 = 132 blocks * 256
    zero_ws_kernel<<<132, 256, 0, stream>>>((float4*)d_ws);

    int blocks = (n + 255) / 256;
    attn_seg_kernel<<<blocks, 256, 0, stream>>>(z, batch, aw1, ab1, aw2, ab2, se, sez, n);
    mlp_kernel<<<N_GRAPHS, 64, 0, stream>>>(se, sez, m1w, m1b, m2w, m2b, m3w, m3b, out);
}

// Round 5
// 131.648 us; speedup vs baseline: 1.0956x; 1.0939x over previous
//
#include <hip/hip_runtime.h>
#include <math.h>

#define N_GRAPHS 4096
#define LATENT 32

typedef float v2f __attribute__((ext_vector_type(2)));

// one DPP-accumulate step; CTRL/RM must be compile-time (template => ICE)
template<int CTRL, int RM>
__device__ __forceinline__ float dpp_add_step(float x) {
    int y = __builtin_amdgcn_update_dpp(0, __float_as_int(x), CTRL, RM, 0xf, false);
    return x + __int_as_float(y);
}
// full wave64 sum, classic gfx9 chain; result valid in lane 63
__device__ __forceinline__ float wave_sum64(float x) {
    x = dpp_add_step<0x111, 0xf>(x);  // row_shr:1
    x = dpp_add_step<0x112, 0xf>(x);  // row_shr:2
    x = dpp_add_step<0x114, 0xf>(x);  // row_shr:4
    x = dpp_add_step<0x118, 0xf>(x);  // row_shr:8
    x = dpp_add_step<0x142, 0xa>(x);  // row_bcast:15 -> rows 1,3
    x = dpp_add_step<0x143, 0xc>(x);  // row_bcast:31 -> rows 2,3
    return x;
}

// Zero the 33*N_GRAPHS-float accumulator workspace
__global__ __launch_bounds__(256) void zero_ws_kernel(float4* __restrict__ ws) {
    ws[blockIdx.x * 256 + threadIdx.x] = float4{0.f, 0.f, 0.f, 0.f};
}

// Fused: per-node attention score + exp + segmented (sorted-batch) weighted sums.
//   se[g]  += sum e_i ;  sez[g][k] += sum e_i * z_i[k]
// GEMM: k-outer, 16 packed v2f accumulators -> v_pk_fma_f32; w1 row k is a
// contiguous 128B scalar load (s_load_dwordx16), double-buffered in SGPRs.
// Reduction: avg segment len ~488 >> 64, so ~87% of waves see one graph ->
// DPP full-wave reduce + lane-63 atomics; boundary waves use segmented scan.
__global__ __launch_bounds__(256, 4) void attn_seg_kernel(
    const float* __restrict__ z, const int* __restrict__ batch,
    const float* __restrict__ w1, const float* __restrict__ b1,
    const float* __restrict__ w2, const float* __restrict__ b2,
    float* __restrict__ se, float* __restrict__ sez, int n)
{
    int i = blockIdx.x * blockDim.x + threadIdx.x;
    int lane = threadIdx.x & 63;
    int iL = (i < n) ? i : (n - 1);       // clamp: extra lanes contribute e=0
    int g = batch[iL];

    float zr[32];
    const float4* zp = reinterpret_cast<const float4*>(z + (size_t)iL * LATENT);
    #pragma unroll
    for (int q = 0; q < 8; ++q) {
        float4 t = zp[q];
        zr[4*q+0] = t.x; zr[4*q+1] = t.y; zr[4*q+2] = t.z; zr[4*q+3] = t.w;
    }

    // h = tanh(z@W1 + b1); alpha = h@w2 + b2  -- packed fp32
    const v2f* b1v = reinterpret_cast<const v2f*>(b1);
    const v2f* w2v = reinterpret_cast<const v2f*>(w2);
    v2f acc2[16];
    #pragma unroll
    for (int jp = 0; jp < 16; ++jp) acc2[jp] = b1v[jp];
    #pragma unroll
    for (int k = 0; k < LATENT; ++k) {
        v2f zk2 = {zr[k], zr[k]};
        const v2f* wr = reinterpret_cast<const v2f*>(w1 + k*LATENT);
        #pragma unroll
        for (int jp = 0; jp < 16; ++jp)
            acc2[jp] = __builtin_elementwise_fma(zk2, wr[jp], acc2[jp]);
    }
    v2f lim_lo = {-15.f, -15.f}, lim_hi = {15.f, 15.f};
    v2f alpha2 = {0.f, 0.f};
    #pragma unroll
    for (int jp = 0; jp < 16; ++jp) {
        v2f x = __builtin_elementwise_min(
                    __builtin_elementwise_max(acc2[jp], lim_lo), lim_hi);
        v2f th;
        float ex = __expf(2.f * x.x);
        float ey = __expf(2.f * x.y);
        th.x = (ex - 1.f) * __builtin_amdgcn_rcpf(ex + 1.f);
        th.y = (ey - 1.f) * __builtin_amdgcn_rcpf(ey + 1.f);
        alpha2 = __builtin_elementwise_fma(th, w2v[jp], alpha2);
    }
    float alpha = alpha2.x + alpha2.y + b2[0];
    // global-max subtraction cancels in the per-graph normalization; skip it.
    float e = (i < n) ? __expf(alpha) : 0.f;

    float v[33];
    v[0] = e;
    #pragma unroll
    for (int k = 0; k < LATENT; ++k) v[k+1] = e * zr[k];

    // fast path: whole wave in one graph (batch sorted)
    bool uniform = (__shfl(g, 0) == __shfl(g, 63));
    if (uniform) {
        #pragma unroll
        for (int t = 0; t < 33; ++t) v[t] = wave_sum64(v[t]);
        if (lane == 63) {
            atomicAdd(&se[g], v[0]);
            #pragma unroll
            for (int k = 0; k < LATENT; ++k)
                atomicAdd(&sez[g*LATENT + k], v[k+1]);
        }
    } else {
        // segmented inclusive scan over the wave
        #pragma unroll
        for (int s = 1; s < 64; s <<= 1) {
            int gprev = __shfl_up(g, s);
            float m = ((lane >= s) && (gprev == g)) ? 1.f : 0.f;
            #pragma unroll
            for (int t = 0; t < 33; ++t) {
                float vv = __shfl_up(v[t], s);
                v[t] = fmaf(m, vv, v[t]);
            }
        }
        int gnext = __shfl_down(g, 1);
        bool tail = (lane == 63) || (gnext != g);
        if (tail) {
            atomicAdd(&se[g], v[0]);
            #pragma unroll
            for (int k = 0; k < LATENT; ++k)
                atomicAdd(&sez[g*LATENT + k], v[k+1]);
        }
    }
}

// One wave per graph: graph_z = sez/(se+1e-8); 32->128->64->1 MLP with sigmoid.
__global__ __launch_bounds__(64) void mlp_kernel(
    const float* __restrict__ se, const float* __restrict__ sez,
    const float* __restrict__ m1w, const float* __restrict__ m1b,
    const float* __restrict__ m2w, const float* __restrict__ m2b,
    const float* __restrict__ m3w, const float* __restrict__ m3b,
    float* __restrict__ out)
{
    int gidx = blockIdx.x;
    int lane = threadIdx.x;
    float inv = 1.f / (se[gidx] + 1e-8f);
    float gz = (lane < LATENT) ? sez[gidx*LATENT + lane] * inv : 0.f;

    float a0 = m1b[lane], a1 = m1b[lane + 64];
    #pragma unroll
    for (int k = 0; k < LATENT; ++k) {
        float zk = __shfl(gz, k);
        a0 = fmaf(zk, m1w[k*128 + lane], a0);
        a1 = fmaf(zk, m1w[k*128 + lane + 64], a1);
    }
    a0 = fmaxf(a0, 0.f); a1 = fmaxf(a1, 0.f);

    float b = m2b[lane];
    #pragma unroll
    for (int k = 0; k < 64; ++k) {
        float xk = __shfl(a0, k);
        b = fmaf(xk, m2w[k*64 + lane], b);
    }
    #pragma unroll
    for (int k = 0; k < 64; ++k) {
        float xk = __shfl(a1, k);
        b = fmaf(xk, m2w[(k+64)*64 + lane], b);
    }
    b = fmaxf(b, 0.f);

    float p = b * m3w[lane];
    #pragma unroll
    for (int s = 32; s >= 1; s >>= 1)
        p += __shfl_xor(p, s);
    if (lane == 0)
        out[gidx] = 1.f / (1.f + __expf(-(p + m3b[0])));
}

extern "C" void kernel_launch(void* const* d_in, const int* in_sizes, int n_in,
                              void* d_out, int out_size, void* d_ws, size_t ws_size,
                              hipStream_t stream)
{
    const float* z    = (const float*)d_in[0];
    const int*   batch= (const int*)d_in[1];
    const float* aw1  = (const float*)d_in[2];
    const float* ab1  = (const float*)d_in[3];
    const float* aw2  = (const float*)d_in[4];
    const float* ab2  = (const float*)d_in[5];
    const float* m1w  = (const float*)d_in[6];
    const float* m1b  = (const float*)d_in[7];
    const float* m2w  = (const float*)d_in[8];
    const float* m2b  = (const float*)d_in[9];
    const float* m3w  = (const float*)d_in[10];
    const float* m3b  = (const float*)d_in[11];
    float* out = (float*)d_out;

    int n = in_sizes[0] / LATENT;   // 2,000,000 nodes

    float* se  = (float*)d_ws;          // [4096]
    float* sez = se + N_GRAPHS;         // [4096][32]

    // N_GRAPHS*33 floats = 135168 floats = 33792 float4 = 132 blocks * 256
    zero_ws_kernel<<<132, 256, 0, stream>>>((float4*)d_ws);

    int blocks = (n + 255) / 256;
    attn_seg_kernel<<<blocks, 256, 0, stream>>>(z, batch, aw1, ab1, aw2, ab2, se, sez, n);
    mlp_kernel<<<N_GRAPHS, 64, 0, stream>>>(se, sez, m1w, m1b, m2w, m2b, m3w, m3b, out);
}